// Round 3
// baseline (675.968 us; speedup 1.0000x reference)
//
#include <hip/hip_runtime.h>

// MUTAN fused bilinear (low-rank Tucker) + ReLU + LayerNorm, MI355X gfx950.
// Round 3: U/V fragments direct global->VGPR (L2-resident, coalesced 64B/row),
// double-buffered hd/hp LDS tiles with single barrier per K-step (2-phase),
// XCD-aware block swizzle (each XCD owns one Z-column slice).

typedef unsigned short u16;
typedef __attribute__((ext_vector_type(8))) short bf16x8;   // 8 bf16 = 4 VGPRs
typedef __attribute__((ext_vector_type(4))) float f32x4;    // MFMA C/D

constexpr int Bq = 4096;   // batch
constexpr int D  = 1024;   // contraction dim
constexpr int Zq = 1024;   // output dim
constexpr int Rk = 16;     // rank
constexpr int BM = 128, BN = 128, BK = 64;

typedef const __attribute__((address_space(1))) void* gas_t;
typedef __attribute__((address_space(3))) void* las_t;

__device__ __forceinline__ u16 f2b(float f) {
  union { float f; unsigned u; } c; c.f = f;
  unsigned r = (c.u + 0x7FFFu + ((c.u >> 16) & 1u)) >> 16;  // RNE
  return (u16)r;
}

// ---- prep: f32 -> bf16 (4M elems, exact grid) ----
__global__ __launch_bounds__(256) void cvt_bf16(const float* __restrict__ s,
                                                u16* __restrict__ d) {
  const int i = blockIdx.x * 256 + threadIdx.x;
  const float4 f = ((const float4*)s)[i];
  union { u16 h[4]; uint2 u; } o;
  o.h[0] = f2b(f.x); o.h[1] = f2b(f.y); o.h[2] = f2b(f.z); o.h[3] = f2b(f.w);
  ((uint2*)d)[i] = o.u;
}

// ---- prep: U [r][k][j] f32 -> Ut [r][j][k] bf16 (32x32 LDS transpose) ----
__global__ __launch_bounds__(256) void transpose_cvt(const float* __restrict__ src,
                                                     u16* __restrict__ dst) {
  __shared__ float t[32][33];
  const int r = blockIdx.z;
  const int j0 = blockIdx.x * 32, k0 = blockIdx.y * 32;
  const int tx = threadIdx.x, ty = threadIdx.y;          // 32 x 8
  const float* s = src + (size_t)r * (D * Zq);
  u16* d = dst + (size_t)r * (D * Zq);
  #pragma unroll
  for (int i = 0; i < 4; ++i)
    t[ty + i * 8][tx] = s[(size_t)(k0 + ty + i * 8) * Zq + j0 + tx];
  __syncthreads();
  #pragma unroll
  for (int i = 0; i < 4; ++i)
    d[(size_t)(j0 + ty + i * 8) * D + k0 + tx] = f2b(t[tx][ty + i * 8]);
}

// swizzled LDS fragment read: tile is [128][BK] bf16 linear in LDS; data was
// staged with source 16B-chunk index XOR'd by (row&7); undo on read.
__device__ __forceinline__ bf16x8 lds_read_swz(const u16* base, int row, int ko) {
  int byte = (row * BK + ko) * 2;
  byte ^= (row & 7) << 4;
  return *(const bf16x8*)((const char*)base + byte);
}

// ---- main: fused bilinear, bf16 MFMA 16x16x32 ----
// 1-D grid 256 (1 block/CU), 512 threads = 8 waves (2m x 4n),
// wave tile 64x32 = 4x2 fragments. A-side (hd,hp) LDS double-buffered;
// B-side (Ut,Vt) fragments loaded straight from global (L2-resident).
__global__ __launch_bounds__(512, 2) void fused_bilinear(
    const u16* __restrict__ hdb, const u16* __restrict__ hpb,
    const u16* __restrict__ Ut, const u16* __restrict__ Vt,
    float* __restrict__ out)
{
  // [buf][tensor(A=hd,B=hp)][128*64]
  __shared__ __align__(16) u16 sT[2][2][BM * BK];

  const int tid  = threadIdx.x;
  const int lane = tid & 63;
  const int wv   = tid >> 6;
  const int wm   = wv >> 2;               // 0..1
  const int wn   = wv & 3;                // 0..3
  const int lm   = lane & 15;             // fragment row/col
  const int lk   = (lane >> 4) << 3;      // k offset: 0,8,16,24

  // XCD swizzle: by = Z-column group (one per XCD), bx = batch-row group.
  const int bid  = blockIdx.x;
  const int by   = bid & 7;
  const int bx   = bid >> 3;
  const int brow = bx * BM;
  const int jcol = by * BN;

  const u16* hdp = hdb + (size_t)brow * D;
  const u16* hpp = hpb + (size_t)brow * D;

  // staging: each tile = 1024 x 16B chunks; thread handles chunks c0, c0+64.
  // global source chunk-in-row XOR-swizzled; LDS dest linear.
  const int cl0 = wv * 128 + lane;
  const int row0 = cl0 >> 3, c0 = cl0 & 7;
  const int cl1 = cl0 + 64;
  const int row1 = cl1 >> 3, c1 = cl1 & 7;
  const int src0 = row0 * D + ((c0 ^ (row0 & 7)) << 3);  // elem offset (pre-kb)
  const int src1 = row1 * D + ((c1 ^ (row1 & 7)) << 3);
  const int ld0  = wv * 1024;          // elem offset in tile
  const int ld1  = ld0 + 512;

  // B-frag per-thread base offset: row j = wn*32 + nf*16 + (l&15), k = lk
  const size_t bofs = (size_t)(wn * 32 + lm) * D + lk;

  f32x4 acc[4][2];
  #pragma unroll
  for (int mf = 0; mf < 4; ++mf)
    #pragma unroll
    for (int nf = 0; nf < 2; ++nf)
      acc[mf][nf] = (f32x4){0.f, 0.f, 0.f, 0.f};

  // prologue: stage tile kt=0
  {
    __builtin_amdgcn_global_load_lds((gas_t)(hdp + src0), (las_t)&sT[0][0][ld0], 16, 0, 0);
    __builtin_amdgcn_global_load_lds((gas_t)(hdp + src1), (las_t)&sT[0][0][ld1], 16, 0, 0);
    __builtin_amdgcn_global_load_lds((gas_t)(hpp + src0), (las_t)&sT[0][1][ld0], 16, 0, 0);
    __builtin_amdgcn_global_load_lds((gas_t)(hpp + src1), (las_t)&sT[0][1][ld1], 16, 0, 0);
  }
  __syncthreads();

  int p = 0;
  for (int r = 0; r < Rk; ++r) {
    const u16* up = Ut + (size_t)r * (D * Zq) + (size_t)jcol * D + bofs;
    const u16* vp = Vt + (size_t)r * (D * Zq) + (size_t)jcol * D + bofs;

    f32x4 au[4][2], av[4][2];
    #pragma unroll
    for (int mf = 0; mf < 4; ++mf)
      #pragma unroll
      for (int nf = 0; nf < 2; ++nf) {
        au[mf][nf] = (f32x4){0.f, 0.f, 0.f, 0.f};
        av[mf][nf] = (f32x4){0.f, 0.f, 0.f, 0.f};
      }

    for (int kt = 0; kt < D / BK; ++kt) {
      const int kb = kt * BK;
      // B fragments straight from global (independent of LDS pipe)
      bf16x8 bu[2][2], bv[2][2];
      #pragma unroll
      for (int kk = 0; kk < 2; ++kk)
        #pragma unroll
        for (int nf = 0; nf < 2; ++nf) {
          const size_t o = (size_t)(nf * 16) * D + kb + kk * 32;
          bu[kk][nf] = *(const bf16x8*)(up + o);
          bv[kk][nf] = *(const bf16x8*)(vp + o);
        }
      // stage next tile into other buffer (wraps identically at rank edge)
      if (!(r == Rk - 1 && kt == D / BK - 1)) {
        const int kbn = ((kt + 1) & (D / BK - 1)) * BK;
        __builtin_amdgcn_global_load_lds((gas_t)(hdp + src0 + kbn), (las_t)&sT[p ^ 1][0][ld0], 16, 0, 0);
        __builtin_amdgcn_global_load_lds((gas_t)(hdp + src1 + kbn), (las_t)&sT[p ^ 1][0][ld1], 16, 0, 0);
        __builtin_amdgcn_global_load_lds((gas_t)(hpp + src0 + kbn), (las_t)&sT[p ^ 1][1][ld0], 16, 0, 0);
        __builtin_amdgcn_global_load_lds((gas_t)(hpp + src1 + kbn), (las_t)&sT[p ^ 1][1][ld1], 16, 0, 0);
      }
      // compute from current buffer
      const u16* tA = sT[p][0];
      const u16* tB = sT[p][1];
      #pragma unroll
      for (int kk = 0; kk < 2; ++kk) {
        const int ko = kk * 32 + lk;
        bf16x8 a[4], b[4];
        #pragma unroll
        for (int mf = 0; mf < 4; ++mf) {
          const int rw = wm * 64 + mf * 16 + lm;
          a[mf] = lds_read_swz(tA, rw, ko);
          b[mf] = lds_read_swz(tB, rw, ko);
        }
        #pragma unroll
        for (int mf = 0; mf < 4; ++mf)
          #pragma unroll
          for (int nf = 0; nf < 2; ++nf) {
            au[mf][nf] = __builtin_amdgcn_mfma_f32_16x16x32_bf16(
                a[mf], bu[kk][nf], au[mf][nf], 0, 0, 0);
            av[mf][nf] = __builtin_amdgcn_mfma_f32_16x16x32_bf16(
                b[mf], bv[kk][nf], av[mf][nf], 0, 0, 0);
          }
      }
      __syncthreads();   // drains stage (vmcnt) + frag reads (lgkmcnt)
      p ^= 1;
    }
    // combine rank r: Hadamard in fragment space (identical C/D layout)
    #pragma unroll
    for (int mf = 0; mf < 4; ++mf)
      #pragma unroll
      for (int nf = 0; nf < 2; ++nf)
        #pragma unroll
        for (int i = 0; i < 4; ++i)
          acc[mf][nf][i] += au[mf][nf][i] * av[mf][nf][i];
  }

  // epilogue: ReLU + store f32. C/D: col = lane&15, row = 4*(lane>>4)+i.
  #pragma unroll
  for (int mf = 0; mf < 4; ++mf)
    #pragma unroll
    for (int nf = 0; nf < 2; ++nf) {
      const int gr = brow + wm * 64 + mf * 16 + ((lane >> 4) << 2);
      const int gc = jcol + wn * 32 + nf * 16 + lm;
      #pragma unroll
      for (int i = 0; i < 4; ++i)
        out[(size_t)(gr + i) * Zq + gc] = fmaxf(acc[mf][nf][i], 0.f);
    }
}

// ---- LayerNorm over rows of d_out, in place. Matches jnp.var (ddof=0). ----
__global__ __launch_bounds__(256) void ln_rows(float* __restrict__ out,
    const float* __restrict__ gamma, const float* __restrict__ beta)
{
  const int row = blockIdx.x;
  float* p = out + (size_t)row * Zq;
  const int t = threadIdx.x;
  float4 v = ((const float4*)p)[t];
  float s = v.x + v.y + v.z + v.w;
  float q = v.x * v.x + v.y * v.y + v.z * v.z + v.w * v.w;
  #pragma unroll
  for (int o = 32; o > 0; o >>= 1) {
    s += __shfl_xor(s, o);
    q += __shfl_xor(q, o);
  }
  __shared__ float ss[4], sq[4];
  if ((t & 63) == 0) { ss[t >> 6] = s; sq[t >> 6] = q; }
  __syncthreads();
  s = ss[0] + ss[1] + ss[2] + ss[3];
  q = sq[0] + sq[1] + sq[2] + sq[3];
  const float mean = s * (1.f / Zq);
  float var = q * (1.f / Zq) - mean * mean;
  var = fmaxf(var, 0.f);
  const float rstd = rsqrtf(var + 1e-5f);
  const float4 g  = ((const float4*)gamma)[t];
  const float4 bb = ((const float4*)beta)[t];
  v.x = (v.x - mean) * rstd * g.x + bb.x;
  v.y = (v.y - mean) * rstd * g.y + bb.y;
  v.z = (v.z - mean) * rstd * g.z + bb.z;
  v.w = (v.w - mean) * rstd * g.w + bb.w;
  ((float4*)p)[t] = v;
}

// ---- fallback (only if ws_size < 80 MB): plain f32, correct but slow ----
__global__ __launch_bounds__(256) void fallback_bilinear(
    const float* __restrict__ hd, const float* __restrict__ hp,
    const float* __restrict__ U, const float* __restrict__ V,
    float* __restrict__ out)
{
  const int j  = blockIdx.x * 256 + threadIdx.x;
  const int b0 = blockIdx.y * 8;
  float acc[8] = {0.f, 0.f, 0.f, 0.f, 0.f, 0.f, 0.f, 0.f};
  for (int r = 0; r < Rk; ++r) {
    float u[8] = {0.f}, v[8] = {0.f};
    const float* Up = U + (size_t)r * (D * Zq) + j;
    const float* Vp = V + (size_t)r * (D * Zq) + j;
    for (int k = 0; k < D; ++k) {
      const float uu = Up[(size_t)k * Zq];
      const float vv = Vp[(size_t)k * Zq];
      #pragma unroll
      for (int bi = 0; bi < 8; ++bi) {
        u[bi] = fmaf(hd[(size_t)(b0 + bi) * D + k], uu, u[bi]);
        v[bi] = fmaf(hp[(size_t)(b0 + bi) * D + k], vv, v[bi]);
      }
    }
    #pragma unroll
    for (int bi = 0; bi < 8; ++bi) acc[bi] += u[bi] * v[bi];
  }
  #pragma unroll
  for (int bi = 0; bi < 8; ++bi)
    out[(size_t)(b0 + bi) * Zq + j] = fmaxf(acc[bi], 0.f);
}

extern "C" void kernel_launch(void* const* d_in, const int* in_sizes, int n_in,
                              void* d_out, int out_size, void* d_ws, size_t ws_size,
                              hipStream_t stream) {
  const float* hd    = (const float*)d_in[0];   // [4096][1024]
  const float* hp    = (const float*)d_in[1];   // [4096][1024]
  const float* U     = (const float*)d_in[2];   // [16][1024][1024]
  const float* V     = (const float*)d_in[3];   // [16][1024][1024]
  const float* gamma = (const float*)d_in[4];   // [1024]
  const float* beta  = (const float*)d_in[5];   // [1024]
  float* out = (float*)d_out;                   // [4096][1024] f32

  const size_t need = 80ull << 20;  // hd,hp bf16 (16MB) + Ut,Vt bf16 (64MB)
  if (ws_size >= need) {
    u16* hdb = (u16*)d_ws;                  // 4096*1024
    u16* hpb = hdb + (size_t)Bq * D;
    u16* Utb = hpb + (size_t)Bq * D;        // 16*1024*1024, [r][j][k]
    u16* Vtb = Utb + (size_t)Rk * D * Zq;

    cvt_bf16<<<4096, 256, 0, stream>>>(hd, hdb);
    cvt_bf16<<<4096, 256, 0, stream>>>(hp, hpb);
    transpose_cvt<<<dim3(32, 32, 16), dim3(32, 8), 0, stream>>>(U, Utb);
    transpose_cvt<<<dim3(32, 32, 16), dim3(32, 8), 0, stream>>>(V, Vtb);
    fused_bilinear<<<256, 512, 0, stream>>>(hdb, hpb, Utb, Vtb, out);
  } else {
    fallback_bilinear<<<dim3(Zq / 256, Bq / 8), 256, 0, stream>>>(hd, hp, U, V, out);
  }
  ln_rows<<<Bq, 256, 0, stream>>>(out, gamma, beta);
}

// Round 4
// 503.141 us; speedup vs baseline: 1.3435x; 1.3435x over previous
//
#include <hip/hip_runtime.h>

// MUTAN fused bilinear (low-rank Tucker) + ReLU + LayerNorm, MI355X gfx950.
// Round 4: fragment-major pre-pack of ALL operands.
//  - hd/hp packed so each 128x64 K-tile is the exact LDS image: staging is
//    linear global_load_lds (2KB contiguous per wave), A-frag ds_read_b128 is
//    lane-consecutive (conflict-free by construction).
//  - U/V packed so each B-fragment is one fully-coalesced 1KB wave load
//    straight global->VGPR (no LDS at all for B).
//  - XCD mapping back to bx%8 (round-3's by-pin caused 1.1GB HBM refetch).

typedef unsigned short u16;
typedef __attribute__((ext_vector_type(8))) short bf16x8;   // 8 bf16 = 4 VGPRs
typedef __attribute__((ext_vector_type(4))) float f32x4;    // MFMA C/D

constexpr int Bq = 4096;   // batch
constexpr int D  = 1024;   // contraction dim
constexpr int Zq = 1024;   // output dim
constexpr int Rk = 16;     // rank
constexpr int BM = 128, BK = 64;
// tile = 1024 chunks of 16B (8 bf16); frag chunk order:
//   A: idx = ((wm*4+mf)*2+kk)*64 + lane   row = wm*64+mf*16+(l&15), k = kk*32+(l>>4)*8
//   B: idx = ((wn*2+nf)*2+kk)*64 + lane   j   = wn*32+nf*16+(l&15), k = kk*32+(l>>4)*8

typedef const __attribute__((address_space(1))) void* gas_t;
typedef __attribute__((address_space(3))) void* las_t;

__device__ __forceinline__ u16 f2b(float f) {
  union { float f; unsigned u; } c; c.f = f;
  unsigned r = (c.u + 0x7FFFu + ((c.u >> 16) & 1u)) >> 16;  // RNE
  return (u16)r;
}

// ---- prep: hd/hp [4096][1024] f32 -> fragment-major bf16 ----
// layout: [bx(32)][kt(16)][chunk(1024)][8]; 524288 chunks per tensor.
__global__ __launch_bounds__(256) void fm_pack_A(const float* __restrict__ src,
                                                 u16* __restrict__ dst) {
  const int g  = blockIdx.x * 256 + threadIdx.x;      // chunk id
  const int c  = g & 1023;
  const int kt = (g >> 10) & 15;
  const int bx = g >> 14;
  const int l  = c & 63;
  const int kk = (c >> 6) & 1;
  const int mf = (c >> 7) & 3;
  const int wm = (c >> 9) & 1;
  const int row = wm * 64 + mf * 16 + (l & 15);
  const int kel = kk * 32 + ((l >> 4) << 3);
  const float* s = src + (size_t)(bx * 128 + row) * D + kt * 64 + kel;
  const float4 f0 = *(const float4*)s;
  const float4 f1 = *(const float4*)(s + 4);
  union { u16 h[8]; uint4 u; } o;
  o.h[0] = f2b(f0.x); o.h[1] = f2b(f0.y); o.h[2] = f2b(f0.z); o.h[3] = f2b(f0.w);
  o.h[4] = f2b(f1.x); o.h[5] = f2b(f1.y); o.h[6] = f2b(f1.z); o.h[7] = f2b(f1.w);
  *(uint4*)(dst + (size_t)g * 8) = o.u;
}

// ---- prep: U/V [r][k][z] f32 -> fragment-major bf16 ----
// layout: [r(16)][jt(8)][kt(16)][chunk(1024)][8]; 2097152 chunks per tensor.
__global__ __launch_bounds__(256) void fm_pack_B(const float* __restrict__ src,
                                                 u16* __restrict__ dst) {
  const int g  = blockIdx.x * 256 + threadIdx.x;      // chunk id
  const int c  = g & 1023;
  const int kt = (g >> 10) & 15;
  const int jt = (g >> 14) & 7;
  const int r  = g >> 17;
  const int l  = c & 63;
  const int kk = (c >> 6) & 1;
  const int nf = (c >> 7) & 1;
  const int wn = (c >> 8) & 3;
  const int j  = jt * 128 + wn * 32 + nf * 16 + (l & 15);
  const int kg = kt * 64 + kk * 32 + ((l >> 4) << 3);
  const float* s = src + (size_t)r * (D * Zq) + (size_t)kg * Zq + j;
  union { u16 h[8]; uint4 u; } o;
  #pragma unroll
  for (int e = 0; e < 8; ++e) o.h[e] = f2b(s[(size_t)e * Zq]);
  *(uint4*)(dst + (size_t)g * 8) = o.u;
}

// ---- main: fused bilinear, bf16 MFMA 16x16x32 ----
// grid (32 bx, 8 jt) -> XCD = bx%8 (hd/hp L2-resident per XCD).
// 512 thr = 8 waves (2m x 4n), wave tile 64x32 = 4x2 frags.
// A (hd,hp): LDS double-buffered fragment-major tiles, linear gload_lds.
// B (U,V): direct global->VGPR, 1KB coalesced per fragment.
__global__ __launch_bounds__(512, 2) void fused_bilinear(
    const u16* __restrict__ hdf, const u16* __restrict__ hpf,
    const u16* __restrict__ Uf, const u16* __restrict__ Vf,
    float* __restrict__ out)
{
  __shared__ __align__(16) u16 sT[2][2][BM * BK];   // 64 KB

  const int tid  = threadIdx.x;
  const int lane = tid & 63;
  const int wv   = tid >> 6;
  const int wm   = wv >> 2;               // 0..1
  const int wn   = wv & 3;                // 0..3

  const int bx = blockIdx.x;              // 0..31 (XCD = bx%8)
  const int jt = blockIdx.y;              // 0..7

  const u16* hdp = hdf + (size_t)bx * 16 * 8192;   // [kt][chunk][8]
  const u16* hpp = hpf + (size_t)bx * 16 * 8192;

  // staging: thread stages chunks c0 and c0+64 of each tensor, linear.
  const int c0 = wv * 128 + lane;
  const int c1 = c0 + 64;

  // A-frag LDS element offsets (lane-consecutive 16B chunks)
  // aofs[mf][kk] = (((wm*4+mf)*2+kk)*64 + lane)*8
  // B-frag global chunk offset within a tile: ((wn*2+nf)*2+kk)*64 + lane

  f32x4 acc[4][2];
  #pragma unroll
  for (int mf = 0; mf < 4; ++mf)
    #pragma unroll
    for (int nf = 0; nf < 2; ++nf)
      acc[mf][nf] = (f32x4){0.f, 0.f, 0.f, 0.f};

  // prologue: stage kt=0 into buffer 0
  __builtin_amdgcn_global_load_lds((gas_t)(hdp + c0 * 8), (las_t)&sT[0][0][c0 * 8], 16, 0, 0);
  __builtin_amdgcn_global_load_lds((gas_t)(hdp + c1 * 8), (las_t)&sT[0][0][c1 * 8], 16, 0, 0);
  __builtin_amdgcn_global_load_lds((gas_t)(hpp + c0 * 8), (las_t)&sT[0][1][c0 * 8], 16, 0, 0);
  __builtin_amdgcn_global_load_lds((gas_t)(hpp + c1 * 8), (las_t)&sT[0][1][c1 * 8], 16, 0, 0);
  __syncthreads();

  int p = 0;
  for (int r = 0; r < Rk; ++r) {
    const u16* up = Uf + ((size_t)(r * 8 + jt) * 16) * 8192;
    const u16* vp = Vf + ((size_t)(r * 8 + jt) * 16) * 8192;

    f32x4 au[4][2], av[4][2];
    #pragma unroll
    for (int mf = 0; mf < 4; ++mf)
      #pragma unroll
      for (int nf = 0; nf < 2; ++nf) {
        au[mf][nf] = (f32x4){0.f, 0.f, 0.f, 0.f};
        av[mf][nf] = (f32x4){0.f, 0.f, 0.f, 0.f};
      }

    for (int kt = 0; kt < 16; ++kt) {
      // B fragments: direct global->VGPR, 1KB coalesced per instruction
      bf16x8 bu[2][2], bv[2][2];
      #pragma unroll
      for (int nf = 0; nf < 2; ++nf)
        #pragma unroll
        for (int kk = 0; kk < 2; ++kk) {
          const int co = kt * 8192 + (((wn * 2 + nf) * 2 + kk) * 64 + lane) * 8;
          bu[nf][kk] = *(const bf16x8*)(up + co);
          bv[nf][kk] = *(const bf16x8*)(vp + co);
        }
      // stage next tile (wraps to kt=0 of next rank; skip only at very end)
      if (!(r == Rk - 1 && kt == 15)) {
        const int ktn = (kt + 1) & 15;
        __builtin_amdgcn_global_load_lds((gas_t)(hdp + ktn * 8192 + c0 * 8), (las_t)&sT[p ^ 1][0][c0 * 8], 16, 0, 0);
        __builtin_amdgcn_global_load_lds((gas_t)(hdp + ktn * 8192 + c1 * 8), (las_t)&sT[p ^ 1][0][c1 * 8], 16, 0, 0);
        __builtin_amdgcn_global_load_lds((gas_t)(hpp + ktn * 8192 + c0 * 8), (las_t)&sT[p ^ 1][1][c0 * 8], 16, 0, 0);
        __builtin_amdgcn_global_load_lds((gas_t)(hpp + ktn * 8192 + c1 * 8), (las_t)&sT[p ^ 1][1][c1 * 8], 16, 0, 0);
      }
      // compute from current buffer
      const u16* tA = sT[p][0];
      const u16* tB = sT[p][1];
      #pragma unroll
      for (int kk = 0; kk < 2; ++kk) {
        bf16x8 a[4], b[4];
        #pragma unroll
        for (int mf = 0; mf < 4; ++mf) {
          const int ao = (((wm * 4 + mf) * 2 + kk) * 64 + lane) * 8;
          a[mf] = *(const bf16x8*)(tA + ao);
          b[mf] = *(const bf16x8*)(tB + ao);
        }
        #pragma unroll
        for (int mf = 0; mf < 4; ++mf)
          #pragma unroll
          for (int nf = 0; nf < 2; ++nf) {
            au[mf][nf] = __builtin_amdgcn_mfma_f32_16x16x32_bf16(
                a[mf], bu[nf][kk], au[mf][nf], 0, 0, 0);
            av[mf][nf] = __builtin_amdgcn_mfma_f32_16x16x32_bf16(
                b[mf], bv[nf][kk], av[mf][nf], 0, 0, 0);
          }
      }
      __syncthreads();   // drains stage (vmcnt) + LDS reads before flip
      p ^= 1;
    }
    // combine rank r: Hadamard in fragment space (identical C/D layout)
    #pragma unroll
    for (int mf = 0; mf < 4; ++mf)
      #pragma unroll
      for (int nf = 0; nf < 2; ++nf)
        #pragma unroll
        for (int i = 0; i < 4; ++i)
          acc[mf][nf][i] += au[mf][nf][i] * av[mf][nf][i];
  }

  // epilogue: ReLU + store f32. C/D: col = lane&15, row = 4*(lane>>4)+i.
  const int brow = bx * BM;
  const int jcol = jt * 128;
  #pragma unroll
  for (int mf = 0; mf < 4; ++mf)
    #pragma unroll
    for (int nf = 0; nf < 2; ++nf) {
      const int gr = brow + wm * 64 + mf * 16 + ((lane >> 4) << 2);
      const int gc = jcol + wn * 32 + nf * 16 + (lane & 15);
      #pragma unroll
      for (int i = 0; i < 4; ++i)
        out[(size_t)(gr + i) * Zq + gc] = fmaxf(acc[mf][nf][i], 0.f);
    }
}

// ---- LayerNorm over rows of d_out, in place. Matches jnp.var (ddof=0). ----
__global__ __launch_bounds__(256) void ln_rows(float* __restrict__ out,
    const float* __restrict__ gamma, const float* __restrict__ beta)
{
  const int row = blockIdx.x;
  float* p = out + (size_t)row * Zq;
  const int t = threadIdx.x;
  float4 v = ((const float4*)p)[t];
  float s = v.x + v.y + v.z + v.w;
  float q = v.x * v.x + v.y * v.y + v.z * v.z + v.w * v.w;
  #pragma unroll
  for (int o = 32; o > 0; o >>= 1) {
    s += __shfl_xor(s, o);
    q += __shfl_xor(q, o);
  }
  __shared__ float ss[4], sq[4];
  if ((t & 63) == 0) { ss[t >> 6] = s; sq[t >> 6] = q; }
  __syncthreads();
  s = ss[0] + ss[1] + ss[2] + ss[3];
  q = sq[0] + sq[1] + sq[2] + sq[3];
  const float mean = s * (1.f / Zq);
  float var = q * (1.f / Zq) - mean * mean;
  var = fmaxf(var, 0.f);
  const float rstd = rsqrtf(var + 1e-5f);
  const float4 g  = ((const float4*)gamma)[t];
  const float4 bb = ((const float4*)beta)[t];
  v.x = (v.x - mean) * rstd * g.x + bb.x;
  v.y = (v.y - mean) * rstd * g.y + bb.y;
  v.z = (v.z - mean) * rstd * g.z + bb.z;
  v.w = (v.w - mean) * rstd * g.w + bb.w;
  ((float4*)p)[t] = v;
}

// ---- fallback (only if ws_size < 80 MB): plain f32, correct but slow ----
__global__ __launch_bounds__(256) void fallback_bilinear(
    const float* __restrict__ hd, const float* __restrict__ hp,
    const float* __restrict__ U, const float* __restrict__ V,
    float* __restrict__ out)
{
  const int j  = blockIdx.x * 256 + threadIdx.x;
  const int b0 = blockIdx.y * 8;
  float acc[8] = {0.f, 0.f, 0.f, 0.f, 0.f, 0.f, 0.f, 0.f};
  for (int r = 0; r < Rk; ++r) {
    float u[8] = {0.f}, v[8] = {0.f};
    const float* Up = U + (size_t)r * (D * Zq) + j;
    const float* Vp = V + (size_t)r * (D * Zq) + j;
    for (int k = 0; k < D; ++k) {
      const float uu = Up[(size_t)k * Zq];
      const float vv = Vp[(size_t)k * Zq];
      #pragma unroll
      for (int bi = 0; bi < 8; ++bi) {
        u[bi] = fmaf(hd[(size_t)(b0 + bi) * D + k], uu, u[bi]);
        v[bi] = fmaf(hp[(size_t)(b0 + bi) * D + k], vv, v[bi]);
      }
    }
    #pragma unroll
    for (int bi = 0; bi < 8; ++bi) acc[bi] += u[bi] * v[bi];
  }
  #pragma unroll
  for (int bi = 0; bi < 8; ++bi)
    out[(size_t)(b0 + bi) * Zq + j] = fmaxf(acc[bi], 0.f);
}

extern "C" void kernel_launch(void* const* d_in, const int* in_sizes, int n_in,
                              void* d_out, int out_size, void* d_ws, size_t ws_size,
                              hipStream_t stream) {
  const float* hd    = (const float*)d_in[0];   // [4096][1024]
  const float* hp    = (const float*)d_in[1];   // [4096][1024]
  const float* U     = (const float*)d_in[2];   // [16][1024][1024]
  const float* V     = (const float*)d_in[3];   // [16][1024][1024]
  const float* gamma = (const float*)d_in[4];   // [1024]
  const float* beta  = (const float*)d_in[5];   // [1024]
  float* out = (float*)d_out;                   // [4096][1024] f32

  const size_t need = 80ull << 20;  // hd,hp fm (16MB) + U,V fm (64MB)
  if (ws_size >= need) {
    u16* hdf = (u16*)d_ws;                   // 4M elems
    u16* hpf = hdf + (size_t)Bq * D;
    u16* Ufm = hpf + (size_t)Bq * D;         // 16M elems each
    u16* Vfm = Ufm + (size_t)Rk * D * Zq;

    fm_pack_A<<<2048, 256, 0, stream>>>(hd, hdf);
    fm_pack_A<<<2048, 256, 0, stream>>>(hp, hpf);
    fm_pack_B<<<8192, 256, 0, stream>>>(U, Ufm);
    fm_pack_B<<<8192, 256, 0, stream>>>(V, Vfm);
    fused_bilinear<<<dim3(32, 8), 512, 0, stream>>>(hdf, hpf, Ufm, Vfm, out);
  } else {
    fallback_bilinear<<<dim3(Zq / 256, Bq / 8), 256, 0, stream>>>(hd, hp, U, V, out);
  }
  ln_rows<<<Bq, 256, 0, stream>>>(out, gamma, beta);
}

// Round 5
// 491.560 us; speedup vs baseline: 1.3751x; 1.0236x over previous
//
#include <hip/hip_runtime.h>

// MUTAN fused bilinear (low-rank Tucker) + ReLU + LayerNorm, MI355X gfx950.
// Round 5: fix the 1-block/CU latency exposure. BM=64, BN=128, 256 thr
// (4 waves, 1m x 4n, wave 64x32), grid (64,8)=512 -> 2 blocks/CU. LDS 32KB
// (dbuf hd/hp frag-major tiles). U/V direct global->VGPR frag-major.

typedef unsigned short u16;
typedef __attribute__((ext_vector_type(8))) short bf16x8;   // 8 bf16 = 4 VGPRs
typedef __attribute__((ext_vector_type(4))) float f32x4;    // MFMA C/D

constexpr int Bq = 4096;   // batch
constexpr int D  = 1024;   // contraction dim
constexpr int Zq = 1024;   // output dim
constexpr int Rk = 16;     // rank
constexpr int BM = 64, BK = 64;
// A tile = 512 chunks of 16B: chunk = (mf*2+kk)*64 + lane
//   row = mf*16 + (l&15), k = kk*32 + (l>>4)*8
// B tile = 1024 chunks: chunk = ((wn*2+nf)*2+kk)*64 + lane
//   col = wn*32 + nf*16 + (l&15), k = kk*32 + (l>>4)*8

typedef const __attribute__((address_space(1))) void* gas_t;
typedef __attribute__((address_space(3))) void* las_t;

__device__ __forceinline__ u16 f2b(float f) {
  union { float f; unsigned u; } c; c.f = f;
  unsigned r = (c.u + 0x7FFFu + ((c.u >> 16) & 1u)) >> 16;  // RNE
  return (u16)r;
}

// ---- prep: hd/hp [4096][1024] f32 -> fragment-major bf16 ----
// layout: [bx(64)][kt(16)][chunk(512)][8]; 524288 chunks per tensor.
__global__ __launch_bounds__(256) void fm_pack_A(const float* __restrict__ src,
                                                 u16* __restrict__ dst) {
  const int g  = blockIdx.x * 256 + threadIdx.x;      // chunk id
  const int c  = g & 511;
  const int kt = (g >> 9) & 15;
  const int bx = g >> 13;
  const int l  = c & 63;
  const int kk = (c >> 6) & 1;
  const int mf = (c >> 7) & 3;
  const int row = mf * 16 + (l & 15);
  const int kel = kk * 32 + ((l >> 4) << 3);
  const float* s = src + (size_t)(bx * 64 + row) * D + kt * 64 + kel;
  const float4 f0 = *(const float4*)s;
  const float4 f1 = *(const float4*)(s + 4);
  union { u16 h[8]; uint4 u; } o;
  o.h[0] = f2b(f0.x); o.h[1] = f2b(f0.y); o.h[2] = f2b(f0.z); o.h[3] = f2b(f0.w);
  o.h[4] = f2b(f1.x); o.h[5] = f2b(f1.y); o.h[6] = f2b(f1.z); o.h[7] = f2b(f1.w);
  *(uint4*)(dst + (size_t)g * 8) = o.u;
}

// ---- prep: U/V [r][k][z] f32 -> fragment-major bf16 ----
// layout: [r(16)][jt(8)][kt(16)][chunk(1024)][8]; 2097152 chunks per tensor.
__global__ __launch_bounds__(256) void fm_pack_B(const float* __restrict__ src,
                                                 u16* __restrict__ dst) {
  const int g  = blockIdx.x * 256 + threadIdx.x;      // chunk id
  const int c  = g & 1023;
  const int kt = (g >> 10) & 15;
  const int jt = (g >> 14) & 7;
  const int r  = g >> 17;
  const int l  = c & 63;
  const int kk = (c >> 6) & 1;
  const int nf = (c >> 7) & 1;
  const int wn = (c >> 8) & 3;
  const int j  = jt * 128 + wn * 32 + nf * 16 + (l & 15);
  const int kg = kt * 64 + kk * 32 + ((l >> 4) << 3);
  const float* s = src + (size_t)r * (D * Zq) + (size_t)kg * Zq + j;
  union { u16 h[8]; uint4 u; } o;
  #pragma unroll
  for (int e = 0; e < 8; ++e) o.h[e] = f2b(s[(size_t)e * Zq]);
  *(uint4*)(dst + (size_t)g * 8) = o.u;
}

// ---- main: fused bilinear, bf16 MFMA 16x16x32 ----
// grid (64 bx, 8 jt) = 512 blocks -> 2 blocks/CU (XCD = bx%8: hd/hp slices
// L2-resident). 256 thr = 4 waves (1m x 4n); wave tile 64x32 = 4mf x 2nf.
__global__ __launch_bounds__(256, 2) void fused_bilinear(
    const u16* __restrict__ hdf, const u16* __restrict__ hpf,
    const u16* __restrict__ Uf, const u16* __restrict__ Vf,
    float* __restrict__ out)
{
  __shared__ __align__(16) u16 sT[2][2][BM * BK];   // 32 KB

  const int tid  = threadIdx.x;
  const int lane = tid & 63;
  const int wn   = tid >> 6;              // 0..3 (wave = n-slice)

  const int bx = blockIdx.x;              // 0..63
  const int jt = blockIdx.y;              // 0..7

  const u16* hdp = hdf + (size_t)bx * 16 * 4096;   // [kt][512 chunks][8]
  const u16* hpp = hpf + (size_t)bx * 16 * 4096;

  // staging: 512 chunks per tensor per kt; thread handles chunks tid, tid+256
  const int c0 = tid;
  const int c1 = tid + 256;

  f32x4 acc[4][2];
  #pragma unroll
  for (int mf = 0; mf < 4; ++mf)
    #pragma unroll
    for (int nf = 0; nf < 2; ++nf)
      acc[mf][nf] = (f32x4){0.f, 0.f, 0.f, 0.f};

  // prologue: stage kt=0 into buffer 0
  __builtin_amdgcn_global_load_lds((gas_t)(hdp + c0 * 8), (las_t)&sT[0][0][c0 * 8], 16, 0, 0);
  __builtin_amdgcn_global_load_lds((gas_t)(hdp + c1 * 8), (las_t)&sT[0][0][c1 * 8], 16, 0, 0);
  __builtin_amdgcn_global_load_lds((gas_t)(hpp + c0 * 8), (las_t)&sT[0][1][c0 * 8], 16, 0, 0);
  __builtin_amdgcn_global_load_lds((gas_t)(hpp + c1 * 8), (las_t)&sT[0][1][c1 * 8], 16, 0, 0);
  __syncthreads();

  int p = 0;
  for (int r = 0; r < Rk; ++r) {
    const u16* up = Uf + ((size_t)(r * 8 + jt) * 16) * 8192;   // [kt][1024][8]
    const u16* vp = Vf + ((size_t)(r * 8 + jt) * 16) * 8192;

    f32x4 au[4][2], av[4][2];
    #pragma unroll
    for (int mf = 0; mf < 4; ++mf)
      #pragma unroll
      for (int nf = 0; nf < 2; ++nf) {
        au[mf][nf] = (f32x4){0.f, 0.f, 0.f, 0.f};
        av[mf][nf] = (f32x4){0.f, 0.f, 0.f, 0.f};
      }

    for (int kt = 0; kt < 16; ++kt) {
      // B fragments: direct global->VGPR, 1KB coalesced per instruction
      bf16x8 bu[2][2], bv[2][2];
      #pragma unroll
      for (int nf = 0; nf < 2; ++nf)
        #pragma unroll
        for (int kk = 0; kk < 2; ++kk) {
          const int co = kt * 8192 + (((wn * 2 + nf) * 2 + kk) * 64 + lane) * 8;
          bu[nf][kk] = *(const bf16x8*)(up + co);
          bv[nf][kk] = *(const bf16x8*)(vp + co);
        }
      // stage next A-tile (wraps to kt=0 of next rank: same data, fine)
      if (!(r == Rk - 1 && kt == 15)) {
        const int ktn = (kt + 1) & 15;
        __builtin_amdgcn_global_load_lds((gas_t)(hdp + ktn * 4096 + c0 * 8), (las_t)&sT[p ^ 1][0][c0 * 8], 16, 0, 0);
        __builtin_amdgcn_global_load_lds((gas_t)(hdp + ktn * 4096 + c1 * 8), (las_t)&sT[p ^ 1][0][c1 * 8], 16, 0, 0);
        __builtin_amdgcn_global_load_lds((gas_t)(hpp + ktn * 4096 + c0 * 8), (las_t)&sT[p ^ 1][1][c0 * 8], 16, 0, 0);
        __builtin_amdgcn_global_load_lds((gas_t)(hpp + ktn * 4096 + c1 * 8), (las_t)&sT[p ^ 1][1][c1 * 8], 16, 0, 0);
      }
      // compute from current buffer
      const u16* tA = sT[p][0];
      const u16* tB = sT[p][1];
      #pragma unroll
      for (int kk = 0; kk < 2; ++kk) {
        bf16x8 a[4], b[4];
        #pragma unroll
        for (int mf = 0; mf < 4; ++mf) {
          const int ao = ((mf * 2 + kk) * 64 + lane) * 8;
          a[mf] = *(const bf16x8*)(tA + ao);
          b[mf] = *(const bf16x8*)(tB + ao);
        }
        #pragma unroll
        for (int mf = 0; mf < 4; ++mf)
          #pragma unroll
          for (int nf = 0; nf < 2; ++nf) {
            au[mf][nf] = __builtin_amdgcn_mfma_f32_16x16x32_bf16(
                a[mf], bu[nf][kk], au[mf][nf], 0, 0, 0);
            av[mf][nf] = __builtin_amdgcn_mfma_f32_16x16x32_bf16(
                b[mf], bv[nf][kk], av[mf][nf], 0, 0, 0);
          }
      }
      __syncthreads();   // drains stage (vmcnt) + LDS reads before flip
      p ^= 1;
    }
    // combine rank r: Hadamard in fragment space (identical C/D layout)
    #pragma unroll
    for (int mf = 0; mf < 4; ++mf)
      #pragma unroll
      for (int nf = 0; nf < 2; ++nf)
        #pragma unroll
        for (int i = 0; i < 4; ++i)
          acc[mf][nf][i] += au[mf][nf][i] * av[mf][nf][i];
  }

  // epilogue: ReLU + store f32. C/D: col = lane&15, row = 4*(lane>>4)+i.
  const int brow = bx * BM;
  const int jcol = jt * 128;
  #pragma unroll
  for (int mf = 0; mf < 4; ++mf)
    #pragma unroll
    for (int nf = 0; nf < 2; ++nf) {
      const int gr = brow + mf * 16 + ((lane >> 4) << 2);
      const int gc = jcol + wn * 32 + nf * 16 + (lane & 15);
      #pragma unroll
      for (int i = 0; i < 4; ++i)
        out[(size_t)(gr + i) * Zq + gc] = fmaxf(acc[mf][nf][i], 0.f);
    }
}

// ---- LayerNorm over rows of d_out, in place. Matches jnp.var (ddof=0). ----
__global__ __launch_bounds__(256) void ln_rows(float* __restrict__ out,
    const float* __restrict__ gamma, const float* __restrict__ beta)
{
  const int row = blockIdx.x;
  float* p = out + (size_t)row * Zq;
  const int t = threadIdx.x;
  float4 v = ((const float4*)p)[t];
  float s = v.x + v.y + v.z + v.w;
  float q = v.x * v.x + v.y * v.y + v.z * v.z + v.w * v.w;
  #pragma unroll
  for (int o = 32; o > 0; o >>= 1) {
    s += __shfl_xor(s, o);
    q += __shfl_xor(q, o);
  }
  __shared__ float ss[4], sq[4];
  if ((t & 63) == 0) { ss[t >> 6] = s; sq[t >> 6] = q; }
  __syncthreads();
  s = ss[0] + ss[1] + ss[2] + ss[3];
  q = sq[0] + sq[1] + sq[2] + sq[3];
  const float mean = s * (1.f / Zq);
  float var = q * (1.f / Zq) - mean * mean;
  var = fmaxf(var, 0.f);
  const float rstd = rsqrtf(var + 1e-5f);
  const float4 g  = ((const float4*)gamma)[t];
  const float4 bb = ((const float4*)beta)[t];
  v.x = (v.x - mean) * rstd * g.x + bb.x;
  v.y = (v.y - mean) * rstd * g.y + bb.y;
  v.z = (v.z - mean) * rstd * g.z + bb.z;
  v.w = (v.w - mean) * rstd * g.w + bb.w;
  ((float4*)p)[t] = v;
}

// ---- fallback (only if ws_size < 80 MB): plain f32, correct but slow ----
__global__ __launch_bounds__(256) void fallback_bilinear(
    const float* __restrict__ hd, const float* __restrict__ hp,
    const float* __restrict__ U, const float* __restrict__ V,
    float* __restrict__ out)
{
  const int j  = blockIdx.x * 256 + threadIdx.x;
  const int b0 = blockIdx.y * 8;
  float acc[8] = {0.f, 0.f, 0.f, 0.f, 0.f, 0.f, 0.f, 0.f};
  for (int r = 0; r < Rk; ++r) {
    float u[8] = {0.f}, v[8] = {0.f};
    const float* Up = U + (size_t)r * (D * Zq) + j;
    const float* Vp = V + (size_t)r * (D * Zq) + j;
    for (int k = 0; k < D; ++k) {
      const float uu = Up[(size_t)k * Zq];
      const float vv = Vp[(size_t)k * Zq];
      #pragma unroll
      for (int bi = 0; bi < 8; ++bi) {
        u[bi] = fmaf(hd[(size_t)(b0 + bi) * D + k], uu, u[bi]);
        v[bi] = fmaf(hp[(size_t)(b0 + bi) * D + k], vv, v[bi]);
      }
    }
    #pragma unroll
    for (int bi = 0; bi < 8; ++bi) acc[bi] += u[bi] * v[bi];
  }
  #pragma unroll
  for (int bi = 0; bi < 8; ++bi)
    out[(size_t)(b0 + bi) * Zq + j] = fmaxf(acc[bi], 0.f);
}

extern "C" void kernel_launch(void* const* d_in, const int* in_sizes, int n_in,
                              void* d_out, int out_size, void* d_ws, size_t ws_size,
                              hipStream_t stream) {
  const float* hd    = (const float*)d_in[0];   // [4096][1024]
  const float* hp    = (const float*)d_in[1];   // [4096][1024]
  const float* U     = (const float*)d_in[2];   // [16][1024][1024]
  const float* V     = (const float*)d_in[3];   // [16][1024][1024]
  const float* gamma = (const float*)d_in[4];   // [1024]
  const float* beta  = (const float*)d_in[5];   // [1024]
  float* out = (float*)d_out;                   // [4096][1024] f32

  const size_t need = 80ull << 20;  // hd,hp fm (16MB) + U,V fm (64MB)
  if (ws_size >= need) {
    u16* hdf = (u16*)d_ws;                   // 4M elems
    u16* hpf = hdf + (size_t)Bq * D;
    u16* Ufm = hpf + (size_t)Bq * D;         // 16M elems each
    u16* Vfm = Ufm + (size_t)Rk * D * Zq;

    fm_pack_A<<<2048, 256, 0, stream>>>(hd, hdf);
    fm_pack_A<<<2048, 256, 0, stream>>>(hp, hpf);
    fm_pack_B<<<8192, 256, 0, stream>>>(U, Ufm);
    fm_pack_B<<<8192, 256, 0, stream>>>(V, Vfm);
    fused_bilinear<<<dim3(64, 8), 256, 0, stream>>>(hdf, hpf, Ufm, Vfm, out);
  } else {
    fallback_bilinear<<<dim3(Zq / 256, Bq / 8), 256, 0, stream>>>(hd, hp, U, V, out);
  }
  ln_rows<<<Bq, 256, 0, stream>>>(out, gamma, beta);
}

// Round 6
// 430.755 us; speedup vs baseline: 1.5693x; 1.1412x over previous
//
#include <hip/hip_runtime.h>

// MUTAN fused bilinear (low-rank Tucker) + ReLU + LayerNorm, MI355X gfx950.
// Round 6: BM=128,BN=128 (1 block/CU, 8 waves) + B-register software pipeline
// (load B(s+1) during compute of s; 2-step unrolled ping-pong reg sets) +
// A LDS double-buffer staged one ahead. Frag-major pre-pack as round 4/5.

typedef unsigned short u16;
typedef __attribute__((ext_vector_type(8))) short bf16x8;   // 8 bf16 = 4 VGPRs
typedef __attribute__((ext_vector_type(4))) float f32x4;    // MFMA C/D

constexpr int Bq = 4096;   // batch
constexpr int D  = 1024;   // contraction dim
constexpr int Zq = 1024;   // output dim
constexpr int Rk = 16;     // rank
// A tile (per kt): 1024 chunks of 16B, chunk = ((wm*4+mf)*2+kk)*64 + lane
//   row = wm*64+mf*16+(l&15), k = kk*32+(l>>4)*8
// B tile (per kt): 1024 chunks, chunk = ((wn*2+nf)*2+kk)*64 + lane
//   col = wn*32+nf*16+(l&15), k = kk*32+(l>>4)*8

typedef const __attribute__((address_space(1))) void* gas_t;
typedef __attribute__((address_space(3))) void* las_t;

__device__ __forceinline__ u16 f2b(float f) {
  union { float f; unsigned u; } c; c.f = f;
  unsigned r = (c.u + 0x7FFFu + ((c.u >> 16) & 1u)) >> 16;  // RNE
  return (u16)r;
}

// ---- prep: hd/hp [4096][1024] f32 -> fragment-major bf16 ----
// layout: [bx(32)][kt(16)][chunk(1024)][8]; 524288 chunks per tensor.
__global__ __launch_bounds__(256) void fm_pack_A(const float* __restrict__ src,
                                                 u16* __restrict__ dst) {
  const int g  = blockIdx.x * 256 + threadIdx.x;      // chunk id
  const int c  = g & 1023;
  const int kt = (g >> 10) & 15;
  const int bx = g >> 14;
  const int l  = c & 63;
  const int kk = (c >> 6) & 1;
  const int mf = (c >> 7) & 3;
  const int wm = (c >> 9) & 1;
  const int row = wm * 64 + mf * 16 + (l & 15);
  const int kel = kk * 32 + ((l >> 4) << 3);
  const float* s = src + (size_t)(bx * 128 + row) * D + kt * 64 + kel;
  const float4 f0 = *(const float4*)s;
  const float4 f1 = *(const float4*)(s + 4);
  union { u16 h[8]; uint4 u; } o;
  o.h[0] = f2b(f0.x); o.h[1] = f2b(f0.y); o.h[2] = f2b(f0.z); o.h[3] = f2b(f0.w);
  o.h[4] = f2b(f1.x); o.h[5] = f2b(f1.y); o.h[6] = f2b(f1.z); o.h[7] = f2b(f1.w);
  *(uint4*)(dst + (size_t)g * 8) = o.u;
}

// ---- prep: U/V [r][k][z] f32 -> fragment-major bf16 ----
// layout: [r(16)][jt(8)][kt(16)][chunk(1024)][8]; 2097152 chunks per tensor.
__global__ __launch_bounds__(256) void fm_pack_B(const float* __restrict__ src,
                                                 u16* __restrict__ dst) {
  const int g  = blockIdx.x * 256 + threadIdx.x;      // chunk id
  const int c  = g & 1023;
  const int kt = (g >> 10) & 15;
  const int jt = (g >> 14) & 7;
  const int r  = g >> 17;
  const int l  = c & 63;
  const int kk = (c >> 6) & 1;
  const int nf = (c >> 7) & 1;
  const int wn = (c >> 8) & 3;
  const int j  = jt * 128 + wn * 32 + nf * 16 + (l & 15);
  const int kg = kt * 64 + kk * 32 + ((l >> 4) << 3);
  const float* s = src + (size_t)r * (D * Zq) + (size_t)kg * Zq + j;
  union { u16 h[8]; uint4 u; } o;
  #pragma unroll
  for (int e = 0; e < 8; ++e) o.h[e] = f2b(s[(size_t)e * Zq]);
  *(uint4*)(dst + (size_t)g * 8) = o.u;
}

#define STAGE(buf, ktile) do {                                                   \
    const int _o = (ktile) * 8192;                                               \
    __builtin_amdgcn_global_load_lds((gas_t)(hdp + _o + c0 * 8), (las_t)&sT[buf][0][c0 * 8], 16, 0, 0); \
    __builtin_amdgcn_global_load_lds((gas_t)(hdp + _o + c1 * 8), (las_t)&sT[buf][0][c1 * 8], 16, 0, 0); \
    __builtin_amdgcn_global_load_lds((gas_t)(hpp + _o + c0 * 8), (las_t)&sT[buf][1][c0 * 8], 16, 0, 0); \
    __builtin_amdgcn_global_load_lds((gas_t)(hpp + _o + c1 * 8), (las_t)&sT[buf][1][c1 * 8], 16, 0, 0); \
  } while (0)

#define LOADB(BU, BV, stp) do {                                                  \
    const u16* _up = Ub + (size_t)((stp) >> 4) * rstride + ((stp) & 15) * 8192;  \
    const u16* _vp = Vb + (size_t)((stp) >> 4) * rstride + ((stp) & 15) * 8192;  \
    _Pragma("unroll")                                                            \
    for (int nf = 0; nf < 2; ++nf)                                               \
      _Pragma("unroll")                                                          \
      for (int kk = 0; kk < 2; ++kk) {                                           \
        BU[nf][kk] = *(const bf16x8*)(_up + bco[nf][kk]);                        \
        BV[nf][kk] = *(const bf16x8*)(_vp + bco[nf][kk]);                        \
      }                                                                          \
  } while (0)

#define COMPUTE(buf, BU, BV) do {                                                \
    const u16* tA = sT[buf][0];                                                  \
    const u16* tB = sT[buf][1];                                                  \
    _Pragma("unroll")                                                            \
    for (int kk = 0; kk < 2; ++kk) {                                             \
      bf16x8 a[4], b[4];                                                         \
      _Pragma("unroll")                                                          \
      for (int mf = 0; mf < 4; ++mf) {                                           \
        const int ao = (((wm * 4 + mf) * 2 + kk) * 64 + lane) * 8;               \
        a[mf] = *(const bf16x8*)(tA + ao);                                       \
        b[mf] = *(const bf16x8*)(tB + ao);                                       \
      }                                                                          \
      _Pragma("unroll")                                                          \
      for (int mf = 0; mf < 4; ++mf)                                             \
        _Pragma("unroll")                                                        \
        for (int nf = 0; nf < 2; ++nf) {                                         \
          au[mf][nf] = __builtin_amdgcn_mfma_f32_16x16x32_bf16(a[mf], BU[nf][kk], au[mf][nf], 0, 0, 0); \
          av[mf][nf] = __builtin_amdgcn_mfma_f32_16x16x32_bf16(b[mf], BV[nf][kk], av[mf][nf], 0, 0, 0); \
        }                                                                        \
    }                                                                            \
  } while (0)

// ---- main: fused bilinear, bf16 MFMA 16x16x32 ----
// grid (32 bx, 8 jt) = 256 blocks = 1/CU. 512 thr = 8 waves (2m x 4n),
// wave tile 64x32 = 4mf x 2nf. A: LDS dbuf, staged 1 ahead. B: VGPR,
// software-pipelined 1 step ahead (ping-pong reg sets, 2-step unroll).
__global__ __launch_bounds__(512, 2) void fused_bilinear(
    const u16* __restrict__ hdf, const u16* __restrict__ hpf,
    const u16* __restrict__ Uf, const u16* __restrict__ Vf,
    float* __restrict__ out)
{
  __shared__ __align__(16) u16 sT[2][2][128 * 64];   // 64 KB

  const int tid  = threadIdx.x;
  const int lane = tid & 63;
  const int wv   = tid >> 6;
  const int wm   = wv >> 2;               // 0..1
  const int wn   = wv & 3;                // 0..3

  const int bx = blockIdx.x;              // 0..31 (XCD = bx%8)
  const int jt = blockIdx.y;              // 0..7

  const u16* hdp = hdf + (size_t)bx * 16 * 8192;     // [kt][1024 chunks][8]
  const u16* hpp = hpf + (size_t)bx * 16 * 8192;
  const u16* Ub  = Uf + (size_t)jt * 16 * 8192;      // + r*rstride + kt*8192
  const u16* Vb  = Vf + (size_t)jt * 16 * 8192;
  const size_t rstride = (size_t)8 * 16 * 8192;

  const int c0 = wv * 128 + lane;
  const int c1 = c0 + 64;

  int bco[2][2];
  #pragma unroll
  for (int nf = 0; nf < 2; ++nf)
    #pragma unroll
    for (int kk = 0; kk < 2; ++kk)
      bco[nf][kk] = (((wn * 2 + nf) * 2 + kk) * 64 + lane) * 8;

  f32x4 acc[4][2], au[4][2], av[4][2];
  #pragma unroll
  for (int mf = 0; mf < 4; ++mf)
    #pragma unroll
    for (int nf = 0; nf < 2; ++nf) {
      acc[mf][nf] = (f32x4){0.f, 0.f, 0.f, 0.f};
      au[mf][nf]  = (f32x4){0.f, 0.f, 0.f, 0.f};
      av[mf][nf]  = (f32x4){0.f, 0.f, 0.f, 0.f};
    }

  bf16x8 bu0[2][2], bv0[2][2], bu1[2][2], bv1[2][2];

  // prologue: stage step 0 tile, load B(step 0)
  STAGE(0, 0);
  LOADB(bu0, bv0, 0);
  __syncthreads();

  #pragma unroll 1
  for (int it = 0; it < 128; ++it) {
    const int s0 = it * 2;        // even step -> buf 0, reg set 0
    const int s1 = s0 + 1;        // odd step  -> buf 1, reg set 1

    // phase A: prefetch s1, compute s0
    STAGE(1, s1 & 15);
    LOADB(bu1, bv1, s1);
    COMPUTE(0, bu0, bv0);
    __syncthreads();

    // phase B: prefetch s1+1, compute s1
    if (s1 < 255) {
      STAGE(0, (s1 + 1) & 15);
      LOADB(bu0, bv0, s1 + 1);
    }
    COMPUTE(1, bu1, bv1);
    // rank boundary: s1&15==15 -> au/av hold full K-sum for rank s1>>4
    if ((s1 & 15) == 15) {
      #pragma unroll
      for (int mf = 0; mf < 4; ++mf)
        #pragma unroll
        for (int nf = 0; nf < 2; ++nf) {
          #pragma unroll
          for (int i = 0; i < 4; ++i)
            acc[mf][nf][i] += au[mf][nf][i] * av[mf][nf][i];
          au[mf][nf] = (f32x4){0.f, 0.f, 0.f, 0.f};
          av[mf][nf] = (f32x4){0.f, 0.f, 0.f, 0.f};
        }
    }
    __syncthreads();
  }

  // epilogue: ReLU + store f32. C/D: col = lane&15, row = 4*(lane>>4)+i.
  const int brow = bx * 128;
  const int jcol = jt * 128;
  #pragma unroll
  for (int mf = 0; mf < 4; ++mf)
    #pragma unroll
    for (int nf = 0; nf < 2; ++nf) {
      const int gr = brow + wm * 64 + mf * 16 + ((lane >> 4) << 2);
      const int gc = jcol + wn * 32 + nf * 16 + (lane & 15);
      #pragma unroll
      for (int i = 0; i < 4; ++i)
        out[(size_t)(gr + i) * Zq + gc] = fmaxf(acc[mf][nf][i], 0.f);
    }
}

// ---- LayerNorm over rows of d_out, in place. Matches jnp.var (ddof=0). ----
__global__ __launch_bounds__(256) void ln_rows(float* __restrict__ out,
    const float* __restrict__ gamma, const float* __restrict__ beta)
{
  const int row = blockIdx.x;
  float* p = out + (size_t)row * Zq;
  const int t = threadIdx.x;
  float4 v = ((const float4*)p)[t];
  float s = v.x + v.y + v.z + v.w;
  float q = v.x * v.x + v.y * v.y + v.z * v.z + v.w * v.w;
  #pragma unroll
  for (int o = 32; o > 0; o >>= 1) {
    s += __shfl_xor(s, o);
    q += __shfl_xor(q, o);
  }
  __shared__ float ss[4], sq[4];
  if ((t & 63) == 0) { ss[t >> 6] = s; sq[t >> 6] = q; }
  __syncthreads();
  s = ss[0] + ss[1] + ss[2] + ss[3];
  q = sq[0] + sq[1] + sq[2] + sq[3];
  const float mean = s * (1.f / Zq);
  float var = q * (1.f / Zq) - mean * mean;
  var = fmaxf(var, 0.f);
  const float rstd = rsqrtf(var + 1e-5f);
  const float4 g  = ((const float4*)gamma)[t];
  const float4 bb = ((const float4*)beta)[t];
  v.x = (v.x - mean) * rstd * g.x + bb.x;
  v.y = (v.y - mean) * rstd * g.y + bb.y;
  v.z = (v.z - mean) * rstd * g.z + bb.z;
  v.w = (v.w - mean) * rstd * g.w + bb.w;
  ((float4*)p)[t] = v;
}

// ---- fallback (only if ws_size < 80 MB): plain f32, correct but slow ----
__global__ __launch_bounds__(256) void fallback_bilinear(
    const float* __restrict__ hd, const float* __restrict__ hp,
    const float* __restrict__ U, const float* __restrict__ V,
    float* __restrict__ out)
{
  const int j  = blockIdx.x * 256 + threadIdx.x;
  const int b0 = blockIdx.y * 8;
  float acc[8] = {0.f, 0.f, 0.f, 0.f, 0.f, 0.f, 0.f, 0.f};
  for (int r = 0; r < Rk; ++r) {
    float u[8] = {0.f}, v[8] = {0.f};
    const float* Up = U + (size_t)r * (D * Zq) + j;
    const float* Vp = V + (size_t)r * (D * Zq) + j;
    for (int k = 0; k < D; ++k) {
      const float uu = Up[(size_t)k * Zq];
      const float vv = Vp[(size_t)k * Zq];
      #pragma unroll
      for (int bi = 0; bi < 8; ++bi) {
        u[bi] = fmaf(hd[(size_t)(b0 + bi) * D + k], uu, u[bi]);
        v[bi] = fmaf(hp[(size_t)(b0 + bi) * D + k], vv, v[bi]);
      }
    }
    #pragma unroll
    for (int bi = 0; bi < 8; ++bi) acc[bi] += u[bi] * v[bi];
  }
  #pragma unroll
  for (int bi = 0; bi < 8; ++bi)
    out[(size_t)(b0 + bi) * Zq + j] = fmaxf(acc[bi], 0.f);
}

extern "C" void kernel_launch(void* const* d_in, const int* in_sizes, int n_in,
                              void* d_out, int out_size, void* d_ws, size_t ws_size,
                              hipStream_t stream) {
  const float* hd    = (const float*)d_in[0];   // [4096][1024]
  const float* hp    = (const float*)d_in[1];   // [4096][1024]
  const float* U     = (const float*)d_in[2];   // [16][1024][1024]
  const float* V     = (const float*)d_in[3];   // [16][1024][1024]
  const float* gamma = (const float*)d_in[4];   // [1024]
  const float* beta  = (const float*)d_in[5];   // [1024]
  float* out = (float*)d_out;                   // [4096][1024] f32

  const size_t need = 80ull << 20;  // hd,hp fm (16MB) + U,V fm (64MB)
  if (ws_size >= need) {
    u16* hdf = (u16*)d_ws;                   // 4M elems
    u16* hpf = hdf + (size_t)Bq * D;
    u16* Ufm = hpf + (size_t)Bq * D;         // 16M elems each
    u16* Vfm = Ufm + (size_t)Rk * D * Zq;

    fm_pack_A<<<2048, 256, 0, stream>>>(hd, hdf);
    fm_pack_A<<<2048, 256, 0, stream>>>(hp, hpf);
    fm_pack_B<<<8192, 256, 0, stream>>>(U, Ufm);
    fm_pack_B<<<8192, 256, 0, stream>>>(V, Vfm);
    fused_bilinear<<<dim3(32, 8), 512, 0, stream>>>(hdf, hpf, Ufm, Vfm, out);
  } else {
    fallback_bilinear<<<dim3(Zq / 256, Bq / 8), 256, 0, stream>>>(hd, hp, U, V, out);
  }
  ln_rows<<<Bq, 256, 0, stream>>>(out, gamma, beta);
}